// Round 2
// baseline (765.234 us; speedup 1.0000x reference)
//
#include <hip/hip_runtime.h>
#include <cstddef>

// Fused single-head causal attention, split into two latency-tolerant kernels.
// B=4096, T=96, C=256, H=64.  out = softmax(mask((x@Wq)(x@Wk)^T * C^-0.5)) @ (x@Wv)
//
// K1 qkv_kernel: [q|k|v] = x @ [Wq|Wk|Wv] (bf16 MFMA), q,k stored bf16 into the
//   d_out byte region (they exactly fill it; overwritten by K2 afterwards), vT
//   stored transposed to d_ws via an LDS transpose (coalesced 32B/thread store).
//   No mid-kernel barriers -> latency hidden by ILP + occupancy.
// K2 attn_kernel: S=qk^T softmax, O=PV. q/k/vT MFMA fragments read DIRECTLY from
//   global (16B-aligned, L2-served re-reads). Only P round-trips LDS (20 KB)
//   -> ~4 blocks/CU resident.

typedef __bf16 bf16x8 __attribute__((ext_vector_type(8)));
typedef float f32x4 __attribute__((ext_vector_type(4)));
typedef unsigned short ushort8 __attribute__((ext_vector_type(8)));

static __device__ __forceinline__ unsigned short f2bf_u16(float f) {
  union { float f; unsigned int u; } c; c.f = f;
  return (unsigned short)((c.u + 0x7FFFu + ((c.u >> 16) & 1u)) >> 16);
}

// ---------------- weight packing: fp32 [256][64] -> bf16 B-fragment order ----
__global__ void pack_w(const float* __restrict__ Wk, const float* __restrict__ Wq,
                       const float* __restrict__ Wv, unsigned short* __restrict__ pack) {
  int idx = blockIdx.x * blockDim.x + threadIdx.x;  // (p,kt,nt,lane), 3*8*4*64 = 6144
  int lane = idx & 63;
  int t = idx >> 6;
  int nt = t & 3; t >>= 2;
  int kt = t & 7; t >>= 3;
  int p  = t;
  if (p >= 3) return;
  const float* W = (p == 0) ? Wk : (p == 1) ? Wq : Wv;
  int k0 = kt * 32 + (lane >> 4) * 8;
  int n  = nt * 16 + (lane & 15);
  unsigned short* dst = pack + (size_t)idx * 8;
#pragma unroll
  for (int j = 0; j < 8; ++j) dst[j] = f2bf_u16(W[(size_t)(k0 + j) * 64 + n]);
}

// ---------------- K1: QKV projection ----------------
#define LDVA 104  // vT transpose tile leading dim (bf16): 208 B rows, 16B-aligned

__global__ __launch_bounds__(384, 4) void qkv_kernel(
    const float* __restrict__ x, const unsigned short* __restrict__ pack,
    unsigned short* __restrict__ qk,   // per b: [0,6144)=q[t][h], [6144,12288)=k[t][h]
    unsigned short* __restrict__ vT) { // per b: vT[h][t], h<64, t<96
  __shared__ __attribute__((aligned(16))) unsigned short vTs[64 * LDVA];

  const int b    = blockIdx.x;
  const int w    = threadIdx.x >> 6;
  const int lane = threadIdx.x & 63;
  const int lo   = lane & 15;
  const int hi   = lane >> 4;

  const float* __restrict__ xb = x + (size_t)b * (96 * 256);

  f32x4 acc[3][4];
#pragma unroll
  for (int p = 0; p < 3; ++p)
#pragma unroll
    for (int nt = 0; nt < 4; ++nt) acc[p][nt] = (f32x4){0.f, 0.f, 0.f, 0.f};

  const int am = 16 * w + lo;
#pragma unroll 2
  for (int kt = 0; kt < 8; ++kt) {
    const float* src = xb + (size_t)am * 256 + kt * 32 + hi * 8;
    f32x4 a0 = *(const f32x4*)src;
    f32x4 a1 = *(const f32x4*)(src + 4);
    union { bf16x8 v; unsigned short u[8]; } af;
#pragma unroll
    for (int j = 0; j < 4; ++j) { af.u[j] = f2bf_u16(a0[j]); af.u[4 + j] = f2bf_u16(a1[j]); }
#pragma unroll
    for (int p = 0; p < 3; ++p) {
#pragma unroll
      for (int nt = 0; nt < 4; ++nt) {
        bf16x8 bf = *(const bf16x8*)(pack + ((size_t)(((p * 8 + kt) * 4 + nt) * 64 + lane) * 8));
        acc[p][nt] = __builtin_amdgcn_mfma_f32_16x16x32_bf16(af.v, bf, acc[p][nt], 0, 0, 0);
      }
    }
  }

  // D layout: row = 16w + hi*4 + r, col = 16nt + lo. acc[0]=k, acc[1]=q, acc[2]=v.
  unsigned short* qb = qk + (size_t)b * 12288;
#pragma unroll
  for (int nt = 0; nt < 4; ++nt) {
#pragma unroll
    for (int r = 0; r < 4; ++r) {
      int row = 16 * w + hi * 4 + r;
      int col = 16 * nt + lo;
      qb[row * 64 + col]        = f2bf_u16(acc[1][nt][r]);   // q
      qb[6144 + row * 64 + col] = f2bf_u16(acc[0][nt][r]);   // k
      vTs[col * LDVA + row]     = f2bf_u16(acc[2][nt][r]);   // v transposed (LDS)
    }
  }
  __syncthreads();

  // coalesced vT store: 64x96 u16 = 6144 elems, 384 threads x 16 u16 (32 B)
  unsigned short* vb = vT + (size_t)b * 6144;
  int h   = threadIdx.x / 6;
  int seg = threadIdx.x - h * 6;
  ushort8 s0 = *(const ushort8*)(vTs + h * LDVA + seg * 16);
  ushort8 s1 = *(const ushort8*)(vTs + h * LDVA + seg * 16 + 8);
  *(ushort8*)(vb + h * 96 + seg * 16)     = s0;
  *(ushort8*)(vb + h * 96 + seg * 16 + 8) = s1;
}

// ---------------- K2: attention ----------------
#define LDP 104

__global__ __launch_bounds__(384, 6) void attn_kernel(
    const unsigned short* qk, const unsigned short* vT, float* out) {
  __shared__ __attribute__((aligned(16))) unsigned short Ps[96 * LDP];
  __shared__ float rowsum[96];

  const int b    = blockIdx.x;
  const int w    = threadIdx.x >> 6;
  const int lane = threadIdx.x & 63;
  const int lo   = lane & 15;
  const int hi   = lane >> 4;

  const unsigned short* qb = qk + (size_t)b * 12288;
  const unsigned short* kb = qb + 6144;

  // ---- S = q @ k^T * (1/16), causal mask, row softmax ----
  f32x4 sacc[6];
#pragma unroll
  for (int jt = 0; jt < 6; ++jt) sacc[jt] = (f32x4){0.f, 0.f, 0.f, 0.f};

  bf16x8 qf0 = *(const bf16x8*)(qb + (16 * w + lo) * 64 + hi * 8);
  bf16x8 qf1 = *(const bf16x8*)(qb + (16 * w + lo) * 64 + 32 + hi * 8);
  for (int jt = 0; jt <= w; ++jt) {
    bf16x8 kf0 = *(const bf16x8*)(kb + (16 * jt + lo) * 64 + hi * 8);
    bf16x8 kf1 = *(const bf16x8*)(kb + (16 * jt + lo) * 64 + 32 + hi * 8);
    sacc[jt] = __builtin_amdgcn_mfma_f32_16x16x32_bf16(qf0, kf0, sacc[jt], 0, 0, 0);
    sacc[jt] = __builtin_amdgcn_mfma_f32_16x16x32_bf16(qf1, kf1, sacc[jt], 0, 0, 0);
  }

#pragma unroll
  for (int r = 0; r < 4; ++r) {
    int row = 16 * w + hi * 4 + r;
    float pr[6];
    float mx = -1e30f;
    for (int jt = 0; jt <= w; ++jt) {
      int col = 16 * jt + lo;
      float s = sacc[jt][r] * 0.0625f;
      s = (col <= row) ? s : -1e30f;
      pr[jt] = s;
      mx = fmaxf(mx, s);
    }
#pragma unroll
    for (int off = 1; off < 16; off <<= 1) mx = fmaxf(mx, __shfl_xor(mx, off, 64));
    float sum = 0.f;
    for (int jt = 0; jt <= w; ++jt) {
      float p = __expf(pr[jt] - mx);
      pr[jt] = p;
      sum += p;
    }
#pragma unroll
    for (int off = 1; off < 16; off <<= 1) sum += __shfl_xor(sum, off, 64);
#pragma unroll
    for (int jt = 0; jt < 6; ++jt) {
      float p = (jt <= w) ? pr[jt] : 0.f;
      Ps[row * LDP + 16 * jt + lo] = f2bf_u16(p);
    }
    if (lo == 0) rowsum[row] = sum;
  }
  __syncthreads();

  // ---- O = P @ v ----
  f32x4 oacc[4];
#pragma unroll
  for (int nt = 0; nt < 4; ++nt) oacc[nt] = (f32x4){0.f, 0.f, 0.f, 0.f};

  const unsigned short* vb = vT + (size_t)b * 6144;
  const int ksmax = (16 * w + 15) >> 5;
  for (int ks = 0; ks <= ksmax; ++ks) {
    bf16x8 pf = *(const bf16x8*)(Ps + (16 * w + lo) * LDP + ks * 32 + hi * 8);
#pragma unroll
    for (int nt = 0; nt < 4; ++nt) {
      bf16x8 vf = *(const bf16x8*)(vb + (16 * nt + lo) * 96 + ks * 32 + hi * 8);
      oacc[nt] = __builtin_amdgcn_mfma_f32_16x16x32_bf16(pf, vf, oacc[nt], 0, 0, 0);
    }
  }

  float* ob = out + (size_t)b * (96 * 64);
#pragma unroll
  for (int r = 0; r < 4; ++r) {
    int row = 16 * w + hi * 4 + r;
    float inv = 1.0f / rowsum[row];
#pragma unroll
    for (int nt = 0; nt < 4; ++nt) {
      ob[row * 64 + 16 * nt + lo] = oacc[nt][r] * inv;
    }
  }
}

extern "C" void kernel_launch(void* const* d_in, const int* in_sizes, int n_in,
                              void* d_out, int out_size, void* d_ws, size_t ws_size,
                              hipStream_t stream) {
  const float* x  = (const float*)d_in[0];
  const float* Wk = (const float*)d_in[1];
  const float* Wq = (const float*)d_in[2];
  const float* Wv = (const float*)d_in[3];
  float* out = (float*)d_out;

  const int B = in_sizes[0] / (96 * 256);

  // d_ws layout: pack (98304 B) | vT (B*6144 u16 = 50,331,648 B)  => ~48.1 MiB
  unsigned short* pack = (unsigned short*)d_ws;
  unsigned short* vT   = (unsigned short*)((char*)d_ws + 98304);
  // q,k live inside d_out's bytes (bf16; exactly fills it; K2 overwrites with out)
  unsigned short* qk   = (unsigned short*)d_out;

  pack_w<<<24, 256, 0, stream>>>(Wk, Wq, Wv, pack);
  qkv_kernel<<<B, 384, 0, stream>>>(x, pack, qk, vT);
  attn_kernel<<<B, 384, 0, stream>>>(qk, vT, out);
}

// Round 3
// 692.891 us; speedup vs baseline: 1.1044x; 1.1044x over previous
//
#include <hip/hip_runtime.h>
#include <cstddef>

// Fused single-head causal attention. B=4096, T=96, C=256, H=64.
// out = softmax(mask((x@Wq)(x@Wk)^T * C^-0.5)) @ (x@Wv)
//
// v3: one block = TWO batch elements, 768 threads = 12 waves (wave w: batch
// half w/6, row-tile 16*(w%6)). bf16 MFMA 16x16x32 everywhere. LDS 68.4 KB
// with aggressive aliasing -> 2 blocks/CU (24 waves) for latency hiding:
//   - q-scratch shares the P buffer (identical row stride -> per-row ownership)
//   - vT overwrites the k buffer after phase 2 (v rides in 8 VGPRs as bf16)
// Weights pre-packed to MFMA B-fragment order in d_ws (96 KB, L2-resident);
// 2 batches/block halves per-batch pack L2 traffic vs v1.

typedef __bf16 bf16x8 __attribute__((ext_vector_type(8)));
typedef float f32x4 __attribute__((ext_vector_type(4)));

static __device__ __forceinline__ unsigned short f2bf_u16(float f) {
  union { float f; unsigned int u; } c; c.f = f;
  return (unsigned short)((c.u + 0x7FFFu + ((c.u >> 16) & 1u)) >> 16);
}

// ---------------- weight packing: fp32 [256][64] -> bf16 B-fragment order ----
// pack[p][kt][nt][lane][j] = bf16(W_p[32*kt + (lane>>4)*8 + j][16*nt + (lane&15)])
__global__ void pack_w(const float* __restrict__ Wk, const float* __restrict__ Wq,
                       const float* __restrict__ Wv, unsigned short* __restrict__ pack) {
  int idx = blockIdx.x * blockDim.x + threadIdx.x;  // 3*8*4*64 = 6144
  int lane = idx & 63;
  int t = idx >> 6;
  int nt = t & 3; t >>= 2;
  int kt = t & 7; t >>= 3;
  int p  = t;
  if (p >= 3) return;
  const float* W = (p == 0) ? Wk : (p == 1) ? Wq : Wv;
  int k0 = kt * 32 + (lane >> 4) * 8;
  int n  = nt * 16 + (lane & 15);
  unsigned short* dst = pack + (size_t)idx * 8;
#pragma unroll
  for (int j = 0; j < 8; ++j) dst[j] = f2bf_u16(W[(size_t)(k0 + j) * 64 + n]);
}

// ---------------- fused attention, 2 batches per block ----------------
#define LDK 72    // k buffer row stride (u16): 144 B rows, 16B-aligned, 2-way bank alias
#define LDP 104   // P / q-scratch row stride (u16): 208 B rows, 16B-aligned
#define LDV 104   // vT row stride inside the recycled k region (64*104 <= 96*72)

__global__ __launch_bounds__(768, 6) void head_fused(
    const float* __restrict__ x, const unsigned short* __restrict__ pack,
    float* __restrict__ out) {
  // ks2: k (phase 2) then vT (phase 3).  SA: q-scratch then P (same row stride!).
  __shared__ __attribute__((aligned(16))) unsigned short ks2[2][96 * LDK];  // 27648 B
  __shared__ __attribute__((aligned(16))) unsigned short SA [2][96 * LDP];  // 39936 B
  __shared__ float rowsum[2][96];                                           //   768 B
  // total 68352 B -> 2 blocks/CU

  const int w    = threadIdx.x >> 6;   // 0..11
  const int half = w >= 6;             // which batch element of the pair
  const int w6   = w - 6 * half;       // row-tile within the batch, 0..5
  const int lane = threadIdx.x & 63;
  const int lo   = lane & 15;
  const int hi   = lane >> 4;

  const int bb = 2 * blockIdx.x + half;
  const float* __restrict__ xb = x + (size_t)bb * (96 * 256);

  // ---- Phase 1: [k|q|v] = x @ [Wk|Wq|Wv]  (M=16 per wave, K=256, N=64 x3) ----
  f32x4 acc[3][4];
#pragma unroll
  for (int p = 0; p < 3; ++p)
#pragma unroll
    for (int nt = 0; nt < 4; ++nt) acc[p][nt] = (f32x4){0.f, 0.f, 0.f, 0.f};

  const int am = 16 * w6 + lo;  // x row this lane supplies for the A-fragment
#pragma unroll 2
  for (int kt = 0; kt < 8; ++kt) {
    const float* src = xb + (size_t)am * 256 + kt * 32 + hi * 8;
    f32x4 a0 = *(const f32x4*)src;
    f32x4 a1 = *(const f32x4*)(src + 4);
    union { bf16x8 v; unsigned short u[8]; } af;
#pragma unroll
    for (int j = 0; j < 4; ++j) { af.u[j] = f2bf_u16(a0[j]); af.u[4 + j] = f2bf_u16(a1[j]); }
#pragma unroll
    for (int p = 0; p < 3; ++p) {
#pragma unroll
      for (int nt = 0; nt < 4; ++nt) {
        bf16x8 bf = *(const bf16x8*)(pack + ((size_t)(((p * 8 + kt) * 4 + nt) * 64 + lane) * 8));
        acc[p][nt] = __builtin_amdgcn_mfma_f32_16x16x32_bf16(af.v, bf, acc[p][nt], 0, 0, 0);
      }
    }
  }

  // D layout: row = 16*w6 + hi*4 + r, col = 16*nt + lo.  acc[0]=k, [1]=q, [2]=v.
  unsigned short vv[16];  // v D-frags packed bf16, carried to phase 3 (8 VGPRs)
#pragma unroll
  for (int nt = 0; nt < 4; ++nt) {
#pragma unroll
    for (int r = 0; r < 4; ++r) {
      int row = 16 * w6 + hi * 4 + r;
      int col = 16 * nt + lo;
      ks2[half][row * LDK + col] = f2bf_u16(acc[0][nt][r]);  // k
      SA [half][row * LDP + col] = f2bf_u16(acc[1][nt][r]);  // q (scratch in P buf)
      vv[nt * 4 + r] = f2bf_u16(acc[2][nt][r]);              // v stays in regs
    }
  }
  __syncthreads();  // barrier 1: k,q visible

  // ---- Phase 2: S = q k^T / 16, causal mask, row softmax, P -> SA ----
  // Per-row ownership makes q-read -> P-write in SA race-free without a barrier:
  // each wave only reads q rows it owns and only writes P rows it owns, and q/P
  // share the same row->address mapping (stride LDP).
  f32x4 sacc[6];
#pragma unroll
  for (int jt = 0; jt < 6; ++jt) sacc[jt] = (f32x4){0.f, 0.f, 0.f, 0.f};

  bf16x8 qf0 = *(const bf16x8*)(SA[half] + (16 * w6 + lo) * LDP + hi * 8);
  bf16x8 qf1 = *(const bf16x8*)(SA[half] + (16 * w6 + lo) * LDP + 32 + hi * 8);
  for (int jt = 0; jt <= w6; ++jt) {   // causal: tiles jt <= w6 only
    bf16x8 kf0 = *(const bf16x8*)(ks2[half] + (16 * jt + lo) * LDK + hi * 8);
    bf16x8 kf1 = *(const bf16x8*)(ks2[half] + (16 * jt + lo) * LDK + 32 + hi * 8);
    sacc[jt] = __builtin_amdgcn_mfma_f32_16x16x32_bf16(qf0, kf0, sacc[jt], 0, 0, 0);
    sacc[jt] = __builtin_amdgcn_mfma_f32_16x16x32_bf16(qf1, kf1, sacc[jt], 0, 0, 0);
  }

#pragma unroll
  for (int r = 0; r < 4; ++r) {
    int row = 16 * w6 + hi * 4 + r;
    float pr[6];
    float mx = -1e30f;
    for (int jt = 0; jt <= w6; ++jt) {
      int col = 16 * jt + lo;
      float s = sacc[jt][r] * 0.0625f;           // * C^-0.5
      s = (col <= row) ? s : -1e30f;
      pr[jt] = s;
      mx = fmaxf(mx, s);
    }
#pragma unroll
    for (int off = 1; off < 16; off <<= 1) mx = fmaxf(mx, __shfl_xor(mx, off, 64));
    float sum = 0.f;
    for (int jt = 0; jt <= w6; ++jt) {
      float p = __expf(pr[jt] - mx);
      pr[jt] = p;
      sum += p;
    }
#pragma unroll
    for (int off = 1; off < 16; off <<= 1) sum += __shfl_xor(sum, off, 64);
#pragma unroll
    for (int jt = 0; jt < 6; ++jt) {
      float p = (jt <= w6) ? pr[jt] : 0.f;
      SA[half][row * LDP + 16 * jt + lo] = f2bf_u16(p);
    }
    if (lo == 0) rowsum[half][row] = sum;
  }
  __syncthreads();  // barrier 2: all k reads done; P,rowsum visible

  // ---- recycle k buffer as vT ----
  unsigned short* vT = ks2[half];  // [64][LDV], 64*104 = 6656 <= 96*72
#pragma unroll
  for (int nt = 0; nt < 4; ++nt) {
#pragma unroll
    for (int r = 0; r < 4; ++r) {
      int row = 16 * w6 + hi * 4 + r;
      int col = 16 * nt + lo;
      vT[col * LDV + row] = vv[nt * 4 + r];
    }
  }
  __syncthreads();  // barrier 3: vT visible

  // ---- Phase 3: O = P @ v, normalize on store ----
  f32x4 oacc[4];
#pragma unroll
  for (int nt = 0; nt < 4; ++nt) oacc[nt] = (f32x4){0.f, 0.f, 0.f, 0.f};

  const int ksmax = (16 * w6 + 15) >> 5;  // skip all-zero K-chunks (causal)
  for (int ks = 0; ks <= ksmax; ++ks) {
    bf16x8 pf = *(const bf16x8*)(SA[half] + (16 * w6 + lo) * LDP + ks * 32 + hi * 8);
#pragma unroll
    for (int nt = 0; nt < 4; ++nt) {
      bf16x8 vf = *(const bf16x8*)(vT + (16 * nt + lo) * LDV + ks * 32 + hi * 8);
      oacc[nt] = __builtin_amdgcn_mfma_f32_16x16x32_bf16(pf, vf, oacc[nt], 0, 0, 0);
    }
  }

  float* __restrict__ ob = out + (size_t)bb * (96 * 64);
#pragma unroll
  for (int r = 0; r < 4; ++r) {
    int row = 16 * w6 + hi * 4 + r;
    float inv = 1.0f / rowsum[half][row];
#pragma unroll
    for (int nt = 0; nt < 4; ++nt) {
      ob[row * 64 + 16 * nt + lo] = oacc[nt][r] * inv;
    }
  }
}

extern "C" void kernel_launch(void* const* d_in, const int* in_sizes, int n_in,
                              void* d_out, int out_size, void* d_ws, size_t ws_size,
                              hipStream_t stream) {
  const float* x  = (const float*)d_in[0];
  const float* Wk = (const float*)d_in[1];
  const float* Wq = (const float*)d_in[2];
  const float* Wv = (const float*)d_in[3];
  float* out = (float*)d_out;
  unsigned short* pack = (unsigned short*)d_ws;  // 96 KB

  const int B = in_sizes[0] / (96 * 256);

  pack_w<<<24, 256, 0, stream>>>(Wk, Wq, Wv, pack);
  head_fused<<<B / 2, 768, 0, stream>>>(x, pack, out);
}

// Round 4
// 659.741 us; speedup vs baseline: 1.1599x; 1.0502x over previous
//
#include <hip/hip_runtime.h>
#include <cstddef>

// Fused single-head causal attention. B=4096, T=96, C=256, H=64.
// out = softmax(mask((x@Wq)(x@Wk)^T * C^-0.5)) @ (x@Wv)
//
// v4: same 2-batch / 768-thread / 12-wave block as v3, but phase 1 no longer
// streams the 96 KB packed-weight array from L2 per wave (2.36 GB aggregate —
// the round-3 latency limiter). Instead the K-loop stages one 12 KB kt-slice
// per iteration into a ping-pong LDS buffer via global_load_lds_dwordx4
// (one 16 B op per thread), m97-style. B-frag reads become stride-1
// ds_read_b128. LDS aliasing (pack dbuf under the P/SA buffer) keeps the
// block at 68.3 KB -> 2 blocks/CU.

typedef __bf16 bf16x8 __attribute__((ext_vector_type(8)));
typedef float f32x4 __attribute__((ext_vector_type(4)));

#define GLOAD_LDS16(gp, lp)                                                     \
  __builtin_amdgcn_global_load_lds(                                             \
      (const __attribute__((address_space(1))) void*)(gp),                      \
      (__attribute__((address_space(3))) void*)(lp), 16, 0, 0)

static __device__ __forceinline__ unsigned short f2bf_u16(float f) {
  union { float f; unsigned int u; } c; c.f = f;
  return (unsigned short)((c.u + 0x7FFFu + ((c.u >> 16) & 1u)) >> 16);
}

// ---- weight packing: fp32 [256][64] -> bf16 B-fragment order, kt-major ----
// pack[kt][p][nt][lane][j] = bf16(W_p[32*kt + (lane>>4)*8 + j][16*nt + (lane&15)])
// One kt-slice (3p x 4nt x 64lane x 8) = 12,288 B contiguous.
__global__ void pack_w(const float* __restrict__ Wk, const float* __restrict__ Wq,
                       const float* __restrict__ Wv, unsigned short* __restrict__ pack) {
  int idx = blockIdx.x * blockDim.x + threadIdx.x;  // 6144 total
  if (idx >= 6144) return;
  int lane = idx & 63;
  int t = idx >> 6;          // t = kt*12 + p*4 + nt
  int nt = t & 3;
  int p  = (t >> 2) % 3;
  int kt = t / 12;
  const float* W = (p == 0) ? Wk : (p == 1) ? Wq : Wv;
  int k0 = kt * 32 + (lane >> 4) * 8;
  int n  = nt * 16 + (lane & 15);
  unsigned short* dst = pack + (size_t)idx * 8;
#pragma unroll
  for (int j = 0; j < 8; ++j) dst[j] = f2bf_u16(W[(size_t)(k0 + j) * 64 + n]);
}

// ---------------- fused attention, 2 batches per block ----------------
#define LDK 72    // k buffer row stride (u16)
#define LDP 104   // P / q-scratch row stride (u16)
#define LDV 104   // vT row stride inside recycled k region (64*104 <= 96*72)

__global__ __launch_bounds__(768, 6) void head_fused(
    const float* __restrict__ x, const unsigned short* __restrict__ pack,
    float* __restrict__ out) {
  // One flat LDS arena with phase-based aliasing:
  //   [0, 24576)      : pack ping-pong, 2 x 12288 B        (phase 1 only)
  //   [0, 39936)      : SA = q-scratch then P, 2x96xLDP u16 (phase 2/3)
  //   [39936, 67584)  : ks2 = k, then vT, 2x96xLDK u16
  //   [67584, 68352)  : rowsum, 2x96 f32
  __shared__ __attribute__((aligned(16))) unsigned char smem[68352];
  unsigned short* SA  = (unsigned short*)smem;
  unsigned short* ks2 = (unsigned short*)(smem + 39936);
  float*          rsm = (float*)(smem + 67584);

  const int w    = threadIdx.x >> 6;   // 0..11
  const int half = w >= 6;
  const int w6   = w - 6 * half;       // row-tile 0..5
  const int lane = threadIdx.x & 63;
  const int lo   = lane & 15;
  const int hi   = lane >> 4;

  const int bb = 2 * blockIdx.x + half;
  const float* __restrict__ xb = x + (size_t)bb * (96 * 256);

  unsigned short* SAh  = SA  + half * (96 * LDP);
  unsigned short* ks2h = ks2 + half * (96 * LDK);
  float*          rsh  = rsm + half * 96;

  // ---- Phase 1: [k|q|v] = x @ [Wk|Wq|Wv], K-loop with LDS-staged B-frags ----
  f32x4 acc[3][4];
#pragma unroll
  for (int p = 0; p < 3; ++p)
#pragma unroll
    for (int nt = 0; nt < 4; ++nt) acc[p][nt] = (f32x4){0.f, 0.f, 0.f, 0.f};

  const int am = 16 * w6 + lo;                       // x row this lane supplies
  const float* xrow = xb + (size_t)am * 256 + hi * 8;

  // stage kt=0 slice; preload kt=0 x regs
  GLOAD_LDS16((const char*)pack + (size_t)threadIdx.x * 16,
              smem + (size_t)w * 1024);
  f32x4 a0 = *(const f32x4*)(xrow);
  f32x4 a1 = *(const f32x4*)(xrow + 4);
  __syncthreads();

  for (int kt = 0; kt < 8; ++kt) {
    const int cur = kt & 1;
    f32x4 na0, na1;
    if (kt < 7) {
      // stage slice kt+1 into the other buffer (its readers drained at the
      // previous barrier); prefetch next x chunk into regs
      GLOAD_LDS16((const char*)pack + (size_t)(kt + 1) * 12288 + (size_t)threadIdx.x * 16,
                  smem + (size_t)(1 - cur) * 12288 + (size_t)w * 1024);
      na0 = *(const f32x4*)(xrow + (kt + 1) * 32);
      na1 = *(const f32x4*)(xrow + (kt + 1) * 32 + 4);
    }
    union { bf16x8 v; unsigned short u[8]; } af;
#pragma unroll
    for (int j = 0; j < 4; ++j) { af.u[j] = f2bf_u16(a0[j]); af.u[4 + j] = f2bf_u16(a1[j]); }
    const unsigned short* pb = (const unsigned short*)(smem + cur * 12288);
#pragma unroll
    for (int p = 0; p < 3; ++p) {
#pragma unroll
      for (int nt = 0; nt < 4; ++nt) {
        bf16x8 bf = *(const bf16x8*)(pb + ((p * 4 + nt) * 64 + lane) * 8);
        acc[p][nt] = __builtin_amdgcn_mfma_f32_16x16x32_bf16(af.v, bf, acc[p][nt], 0, 0, 0);
      }
    }
    if (kt < 7) { a0 = na0; a1 = na1; }
    __syncthreads();   // staged slice kt+1 complete; pack reads of cur drained
  }
  // (last barrier above also fences pack-LDS reads before SA is overwritten)

  // D layout: row = 16*w6 + hi*4 + r, col = 16*nt + lo.  acc[0]=k, [1]=q, [2]=v.
  unsigned short vv[16];  // v D-frags, carried in regs to phase 3
#pragma unroll
  for (int nt = 0; nt < 4; ++nt) {
#pragma unroll
    for (int r = 0; r < 4; ++r) {
      int row = 16 * w6 + hi * 4 + r;
      int col = 16 * nt + lo;
      ks2h[row * LDK + col] = f2bf_u16(acc[0][nt][r]);  // k
      SAh [row * LDP + col] = f2bf_u16(acc[1][nt][r]);  // q (scratch in P buf)
      vv[nt * 4 + r] = f2bf_u16(acc[2][nt][r]);         // v stays in regs
    }
  }
  __syncthreads();  // k,q visible

  // ---- Phase 2: S = q k^T / 16, causal mask, row softmax, P -> SA ----
  // q-read -> P-write in SA is race-free: per-row ownership, same row mapping.
  f32x4 sacc[6];
#pragma unroll
  for (int jt = 0; jt < 6; ++jt) sacc[jt] = (f32x4){0.f, 0.f, 0.f, 0.f};

  bf16x8 qf0 = *(const bf16x8*)(SAh + (16 * w6 + lo) * LDP + hi * 8);
  bf16x8 qf1 = *(const bf16x8*)(SAh + (16 * w6 + lo) * LDP + 32 + hi * 8);
  for (int jt = 0; jt <= w6; ++jt) {   // causal: tiles jt <= w6 only
    bf16x8 kf0 = *(const bf16x8*)(ks2h + (16 * jt + lo) * LDK + hi * 8);
    bf16x8 kf1 = *(const bf16x8*)(ks2h + (16 * jt + lo) * LDK + 32 + hi * 8);
    sacc[jt] = __builtin_amdgcn_mfma_f32_16x16x32_bf16(qf0, kf0, sacc[jt], 0, 0, 0);
    sacc[jt] = __builtin_amdgcn_mfma_f32_16x16x32_bf16(qf1, kf1, sacc[jt], 0, 0, 0);
  }

#pragma unroll
  for (int r = 0; r < 4; ++r) {
    int row = 16 * w6 + hi * 4 + r;
    float pr[6];
    float mx = -1e30f;
    for (int jt = 0; jt <= w6; ++jt) {
      int col = 16 * jt + lo;
      float s = sacc[jt][r] * 0.0625f;           // * C^-0.5
      s = (col <= row) ? s : -1e30f;
      pr[jt] = s;
      mx = fmaxf(mx, s);
    }
#pragma unroll
    for (int off = 1; off < 16; off <<= 1) mx = fmaxf(mx, __shfl_xor(mx, off, 64));
    float sum = 0.f;
    for (int jt = 0; jt <= w6; ++jt) {
      float p = __expf(pr[jt] - mx);
      pr[jt] = p;
      sum += p;
    }
#pragma unroll
    for (int off = 1; off < 16; off <<= 1) sum += __shfl_xor(sum, off, 64);
#pragma unroll
    for (int jt = 0; jt < 6; ++jt) {
      float p = (jt <= w6) ? pr[jt] : 0.f;
      SAh[row * LDP + 16 * jt + lo] = f2bf_u16(p);
    }
    if (lo == 0) rsh[row] = sum;
  }
  __syncthreads();  // all k reads done; P,rowsum visible

  // ---- recycle k buffer as vT ----
  unsigned short* vT = ks2h;  // [64][LDV], 64*104 = 6656 <= 96*72
#pragma unroll
  for (int nt = 0; nt < 4; ++nt) {
#pragma unroll
    for (int r = 0; r < 4; ++r) {
      int row = 16 * w6 + hi * 4 + r;
      int col = 16 * nt + lo;
      vT[col * LDV + row] = vv[nt * 4 + r];
    }
  }
  __syncthreads();  // vT visible

  // ---- Phase 3: O = P @ v, normalize on store ----
  f32x4 oacc[4];
#pragma unroll
  for (int nt = 0; nt < 4; ++nt) oacc[nt] = (f32x4){0.f, 0.f, 0.f, 0.f};

  const int ksmax = (16 * w6 + 15) >> 5;  // skip all-zero K-chunks (causal)
  for (int ks = 0; ks <= ksmax; ++ks) {
    bf16x8 pf = *(const bf16x8*)(SAh + (16 * w6 + lo) * LDP + ks * 32 + hi * 8);
#pragma unroll
    for (int nt = 0; nt < 4; ++nt) {
      bf16x8 vf = *(const bf16x8*)(vT + (16 * nt + lo) * LDV + ks * 32 + hi * 8);
      oacc[nt] = __builtin_amdgcn_mfma_f32_16x16x32_bf16(pf, vf, oacc[nt], 0, 0, 0);
    }
  }

  float* __restrict__ ob = out + (size_t)bb * (96 * 64);
#pragma unroll
  for (int r = 0; r < 4; ++r) {
    int row = 16 * w6 + hi * 4 + r;
    float inv = 1.0f / rsh[row];
#pragma unroll
    for (int nt = 0; nt < 4; ++nt) {
      ob[row * 64 + 16 * nt + lo] = oacc[nt][r] * inv;
    }
  }
}

extern "C" void kernel_launch(void* const* d_in, const int* in_sizes, int n_in,
                              void* d_out, int out_size, void* d_ws, size_t ws_size,
                              hipStream_t stream) {
  const float* x  = (const float*)d_in[0];
  const float* Wk = (const float*)d_in[1];
  const float* Wq = (const float*)d_in[2];
  const float* Wv = (const float*)d_in[3];
  float* out = (float*)d_out;
  unsigned short* pack = (unsigned short*)d_ws;  // 96 KB, kt-major slices

  const int B = in_sizes[0] / (96 * 256);

  pack_w<<<24, 256, 0, stream>>>(Wk, Wq, Wv, pack);
  head_fused<<<B / 2, 768, 0, stream>>>(x, pack, out);
}